// Round 10
// baseline (408.545 us; speedup 1.0000x reference)
//
#include <hip/hip_runtime.h>
#include <hip/hip_bf16.h>
#include <stdint.h>

// Problem constants: B=32, T=256, M=2048, C=F=256, K=3 (pad 1), NB=256
#define DUR_OFF 16777216
#define PIT_OFF 16785408
#define ENE_OFF 16850944
#define MEL_OFF 16916480

typedef __attribute__((ext_vector_type(8))) short short8;
typedef __attribute__((ext_vector_type(4))) float f32x4;

__device__ __forceinline__ void async16(const void* g, void* l) {
  __builtin_amdgcn_global_load_lds((__attribute__((address_space(1))) void*)g,
                                   (__attribute__((address_space(3))) void*)l, 16, 0, 0);
}

__device__ __forceinline__ unsigned short bfu(float f) {
  __hip_bfloat16 h = __float2bfloat16(f);
  return __builtin_bit_cast(unsigned short, h);
}
__device__ __forceinline__ float f_from_bf(unsigned short u) {
  return __builtin_bit_cast(float, (unsigned)u << 16);
}

// Zero the two pad rows (t=-1, t=L) of the three padded [B][L+2][256] bf16 buffers.
__global__ void zero2_kernel(__hip_bfloat16* __restrict__ xb, __hip_bfloat16* __restrict__ M1,
                             __hip_bfloat16* __restrict__ M2) {
  int buf = blockIdx.x >> 6, sub = blockIdx.x & 63;
  int b = sub >> 1, top = sub & 1;
  __hip_bfloat16* p; int L;
  if (buf == 0) { p = xb; L = 256; }
  else if (buf == 1) { p = M1; L = 2048; }
  else { p = M2; L = 2048; }
  size_t row = (size_t)b * (L + 2) + (top ? (L + 1) : 0);
  p[row * 256 + threadIdx.x] = __float2bfloat16(0.0f);
}

// Pack all 6 conv weights [F=256][C=256][K=3] f32 (torch OIH) into MFMA-fragment-linear
// bf16 layout: Wfrag[wsel][fb][ni][tap][ks][lane][e], 16 B per (..,lane) chunk, so a wave's
// B-fragment load is base + lane*16 (fully coalesced 1 KB).
//   f = fb*64 + ni*16 + (lane&15);  c = ks*32 + (lane>>4)*8 + e;  kk = tap*256 + c
__global__ void packfrag_kernel(const float* __restrict__ w0, const float* __restrict__ w1,
                                const float* __restrict__ w2, const float* __restrict__ w3,
                                const float* __restrict__ w4, const float* __restrict__ w5,
                                __hip_bfloat16* __restrict__ wpbase) {
  int t = blockIdx.x * 256 + threadIdx.x;   // 147456 total = 6 * 24576 chunks
  int wsel = t / 24576;
  int rem = t % 24576;
  const float* w = wsel == 0 ? w0 : wsel == 1 ? w1 : wsel == 2 ? w2
                 : wsel == 3 ? w3 : wsel == 4 ? w4 : w5;
  __hip_bfloat16* wp = wpbase + (size_t)wsel * 196608;
  int L = rem & 63;
  int ks = (rem >> 6) & 7;
  int q = rem >> 9;            // (fb*4+ni)*3 + tap
  int tap = q % 3, r = q / 3;
  int ni = r & 3, fb = r >> 2;
  int f = fb * 64 + ni * 16 + (L & 15);
  int cb = ks * 32 + ((L >> 4) << 3);
  short8 o;
#pragma unroll
  for (int e = 0; e < 8; ++e)
    o[e] = (short)bfu(w[((size_t)f * 256 + cb + e) * 3 + tap]);
  *(short8*)(wp + (size_t)rem * 8) = o;
}

// x [32][256][256] f32 -> xb [32][258][256] bf16 (row t -> padded row t+1)
__global__ void cvt_pad_kernel(const float* __restrict__ x, __hip_bfloat16* __restrict__ xb) {
  int idx = blockIdx.x * 256 + threadIdx.x;
  float4 v = ((const float4*)x)[idx];
  int c4 = idx & 63;
  int rowi = idx >> 6;
  int b = rowi >> 8, t = rowi & 255;
  ushort4 o;
  o.x = bfu(v.x); o.y = bfu(v.y); o.z = bfu(v.z); o.w = bfu(v.w);
  ((ushort4*)(xb + ((size_t)b * 258 + t + 1) * 256))[c4] = o;
}

// Length regulate (in-block cumsum of true_duration) -> bf16 padded M1; chunk0 writes mel_len.
__global__ void gather_kernel(const __hip_bfloat16* __restrict__ xb, const int* __restrict__ dur,
                              __hip_bfloat16* __restrict__ outB, float* __restrict__ mel) {
  __shared__ int scs[256];
  __shared__ int sidx[64];
  __shared__ int sval[64];
  int bch = blockIdx.x >> 5;
  int m0 = (blockIdx.x & 31) << 6;
  int tid = threadIdx.x;
  scs[tid] = dur[bch * 256 + tid];
  __syncthreads();
  for (int off = 1; off < 256; off <<= 1) {
    int add = (tid >= off) ? scs[tid - off] : 0;
    __syncthreads();
    scs[tid] += add;
    __syncthreads();
  }
  int total = scs[255];
  if (tid == 0 && (blockIdx.x & 31) == 0)
    mel[bch] = (float)(total < 2048 ? total : 2048);
  if (tid < 64) {
    int m = m0 + tid;
    int lo = 0, hi = 256;
    while (lo < hi) { int mid = (lo + hi) >> 1; if (scs[mid] <= m) lo = mid + 1; else hi = mid; }
    sidx[tid] = lo < 255 ? lo : 255;
    sval[tid] = (m < total);
  }
  __syncthreads();
  int lane = tid & 63, rs = tid >> 6;
  for (int r = rs; r < 64; r += 4) {
    ushort4 o = make_ushort4(0, 0, 0, 0);
    if (sval[r])
      o = ((const ushort4*)(xb + ((size_t)bch * 258 + sidx[r] + 1) * 256))[lane];
    ((ushort4*)(outB + ((size_t)bch * 2050 + m0 + r + 1) * 256))[lane] = o;
  }
}

// Fused double embedding add: M2 = bf16(M1 + pemb[idx_p]); out = (M1 + pemb) + eemb[idx_e] (f32)
__global__ void addemb_kernel(const float* __restrict__ tp, const float* __restrict__ te,
                              const float* __restrict__ pq, const float* __restrict__ eq,
                              const float* __restrict__ pemb, const float* __restrict__ eemb,
                              const __hip_bfloat16* __restrict__ M1, __hip_bfloat16* __restrict__ M2,
                              float* __restrict__ out) {
  __shared__ float sp[255], se[255];
  __shared__ int sip[64], sie[64];
  int bch = blockIdx.x >> 5;
  int m0 = (blockIdx.x & 31) << 6;
  int tid = threadIdx.x;
  if (tid < 255) { sp[tid] = pq[tid]; se[tid] = eq[tid]; }
  __syncthreads();
  if (tid < 64) {
    float xv = tp[bch * 2048 + m0 + tid];
    int lo = 0, hi = 255;
    while (lo < hi) { int mid = (lo + hi) >> 1; if (sp[mid] <= xv) lo = mid + 1; else hi = mid; }
    sip[tid] = lo;
    float ev = te[bch * 2048 + m0 + tid];
    lo = 0; hi = 255;
    while (lo < hi) { int mid = (lo + hi) >> 1; if (se[mid] <= ev) lo = mid + 1; else hi = mid; }
    sie[tid] = lo;
  }
  __syncthreads();
  int lane = tid & 63, rs = tid >> 6;
  for (int r = rs; r < 64; r += 4) {
    ushort4 mv = ((const ushort4*)(M1 + ((size_t)bch * 2050 + m0 + r + 1) * 256))[lane];
    float4 ep = ((const float4*)(pemb + (size_t)sip[r] * 256))[lane];
    float4 ee = ((const float4*)(eemb + (size_t)sie[r] * 256))[lane];
    float4 v;
    v.x = f_from_bf(mv.x) + ep.x; v.y = f_from_bf(mv.y) + ep.y;
    v.z = f_from_bf(mv.z) + ep.z; v.w = f_from_bf(mv.w) + ep.w;
    ushort4 o;
    o.x = bfu(v.x); o.y = bfu(v.y); o.z = bfu(v.z); o.w = bfu(v.w);
    ((ushort4*)(M2 + ((size_t)bch * 2050 + m0 + r + 1) * 256))[lane] = o;
    float4 w;
    w.x = v.x + ee.x; w.y = v.y + ee.y; w.z = v.z + ee.z; w.w = v.w + ee.w;
    ((float4*)(out + ((size_t)bch * 2048 + m0 + r) * 256))[lane] = w;
  }
}

// Load the 4 B fragments of K-slice s (s = tap*8+ks) for this wave's 64-col block.
__device__ __forceinline__ void loadB4(const char* Wb, int s, short8 (&dst)[4]) {
  int tap = s >> 3, ks = s & 7;
#pragma unroll
  for (int ni = 0; ni < 4; ++ni)
    dst[ni] = *(const short8*)(Wb + ((((ni * 3 + tap) << 3) + ks) << 10));
}

// FULLY-FUSED predictor: conv1(K=3)+bias+ReLU+LN -> (LDS) -> conv2+bias+ReLU+LN ->
// Linear(F->1)+ReLU -> Sout[B][L]. The h1 intermediate NEVER touches global memory.
// Per block: 64 output rows x full 256 cols; 4 waves, wave = 64-col slice.
//   conv1: A tile = padded rows t0-1 .. t0+80 (82 rows, 42KB, staged once via
//     global_load_lds w/ pre-swizzled source); 5 M-tiles (80 h1 rows t0-1..t0+78,
//     rows >= t0+65 are waste/dead). LN1 per row over 256 cols (cross-wave via lred).
//   h1 rows t0-1..t0+64 (66) written bf16 into the SAME LDS buffer (A is dead),
//     XOR-swizzled; boundary rows r=-1 / r=L forced to 0 (zero padding semantics).
//   conv2: 4 M-tiles from LDS h1; LN2 + dot(wl) + bl -> ReLU -> 64 scalars.
// B fragments stream from L2 (fragment-linear Wf, coalesced 1KB loads).
__global__ __launch_bounds__(256, 3)
void fused_pred(const __hip_bfloat16* __restrict__ Ap, const __hip_bfloat16* __restrict__ Wf1,
                const __hip_bfloat16* __restrict__ Wf2,
                const float* __restrict__ b1, const float* __restrict__ g1,
                const float* __restrict__ be1,
                const float* __restrict__ b2, const float* __restrict__ g2,
                const float* __restrict__ be2,
                const float* __restrict__ wl, const float* __restrict__ blp,
                float* __restrict__ Sout, int L) {
  __shared__ char lA[41984];        // 82 rows x 512B; reused as h1 buffer (66 rows)
  __shared__ float lred[80 * 8];
  __shared__ float lstat[80 * 2];

  const int tid = threadIdx.x;
  const int wid = tid >> 6;
  const int lane = tid & 63;
  const int wn = wid;
  const int tiles = L >> 6;
  const int b = blockIdx.x / tiles;
  const int t0 = (blockIdx.x % tiles) << 6;
  const int rlane = lane & 15;
  const int colp = (lane >> 4) << 4;
  const int rbase = (lane >> 4) << 2;
  const int cb0 = (wn << 6) + rlane;

  // ---- stage A: padded rows t0-1 .. t0+80 (82 rows). May read up to 512B before /
  // ~8KB after the buffer for edge tiles — always within d_ws; values only feed dead rows.
  const char* Asrc = (const char*)(Ap + ((size_t)b * (L + 2) + t0) * 256) - 512;
#pragma unroll
  for (int j = 0; j < 11; ++j) {
    int off = j * 4096 + tid * 16;
    if (off < 41984) {
      int so = off ^ (((off >> 9) & 7) << 4);
      async16(Asrc + so, lA + off);
    }
  }

  const char* Wb1 = (const char*)Wf1 + (size_t)wn * 98304 + lane * 16;
  const char* Wb2 = (const char*)Wf2 + (size_t)wn * 98304 + lane * 16;

  f32x4 acc1[5][4];
  const f32x4 zero4 = {0.f, 0.f, 0.f, 0.f};
#pragma unroll
  for (int i = 0; i < 5; ++i)
#pragma unroll
    for (int j = 0; j < 4; ++j) acc1[i][j] = zero4;

  __syncthreads();  // A tile resident

  // ---- conv1 K-loop: 24 slices, MI=5 ----
#pragma unroll 1
  for (int s = 0; s < 24; ++s) {
    const int tap = s >> 3, ks = s & 7;
    short8 bv[4];
    loadB4(Wb1, s, bv);
    const int xorv = ((tap + rlane) & 7) << 4;
    short8 av[5];
#pragma unroll
    for (int mi = 0; mi < 5; ++mi) {
      int a = (tap + (mi << 4) + rlane) * 512 + (ks << 6) + colp;
      av[mi] = *(const short8*)(lA + (a ^ xorv));
    }
#pragma unroll
    for (int mi = 0; mi < 5; ++mi)
#pragma unroll
      for (int ni = 0; ni < 4; ++ni)
        acc1[mi][ni] =
            __builtin_amdgcn_mfma_f32_16x16x32_bf16(av[mi], bv[ni], acc1[mi][ni], 0, 0, 0);
  }

  // ---- LN1 stats over 80 rows ----
  float bi1[4], gg1[4], bb1[4];
#pragma unroll
  for (int ni = 0; ni < 4; ++ni) {
    int col = cb0 + (ni << 4);
    bi1[ni] = b1[col]; gg1[ni] = g1[col]; bb1[ni] = be1[col];
  }
#pragma unroll
  for (int mi = 0; mi < 5; ++mi) {
#pragma unroll
    for (int j = 0; j < 4; ++j) {
      float s = 0.f, s2 = 0.f;
#pragma unroll
      for (int ni = 0; ni < 4; ++ni) {
        float r = fmaxf(acc1[mi][ni][j] + bi1[ni], 0.f);
        s += r; s2 += r * r;
      }
#pragma unroll
      for (int d = 1; d < 16; d <<= 1) { s += __shfl_xor(s, d); s2 += __shfl_xor(s2, d); }
      if ((lane & 15) == 0) {
        int lr = (mi << 4) + rbase + j;
        lred[lr * 8 + wn] = s;
        lred[lr * 8 + 4 + wn] = s2;
      }
    }
  }
  __syncthreads();
  if (tid < 80) {
    float s = lred[tid * 8] + lred[tid * 8 + 1] + lred[tid * 8 + 2] + lred[tid * 8 + 3];
    float s2 = lred[tid * 8 + 4] + lred[tid * 8 + 5] + lred[tid * 8 + 6] + lred[tid * 8 + 7];
    float mean = s * (1.f / 256.f);
    float var = fmaxf(s2 * (1.f / 256.f) - mean * mean, 0.f);
    lstat[tid * 2] = mean;
    lstat[tid * 2 + 1] = rsqrtf(var + 1e-5f);
  }
  __syncthreads();

  // ---- write h1 rows 0..65 (= global rows t0-1 .. t0+64) into lA, swizzled bf16 ----
#pragma unroll
  for (int mi = 0; mi < 5; ++mi) {
#pragma unroll
    for (int j = 0; j < 4; ++j) {
      int lr = (mi << 4) + rbase + j;
      if (lr < 66) {
        int rg = t0 - 1 + lr;
        bool dead = (rg < 0) || (rg >= L);
        float mean = lstat[lr * 2], rstd = lstat[lr * 2 + 1];
#pragma unroll
        for (int ni = 0; ni < 4; ++ni) {
          float r = fmaxf(acc1[mi][ni][j] + bi1[ni], 0.f);
          float v = dead ? 0.f : (r - mean) * rstd * gg1[ni] + bb1[ni];
          int byte = (lr * 512 + ((cb0 + (ni << 4)) << 1)) ^ ((lr & 7) << 4);
          *(__hip_bfloat16*)(lA + byte) = __float2bfloat16(v);
        }
      }
    }
  }
  __syncthreads();  // h1 resident

  // ---- conv2 K-loop: 24 slices, MI=4, A from LDS h1 ----
  f32x4 acc2[4][4];
#pragma unroll
  for (int i = 0; i < 4; ++i)
#pragma unroll
    for (int j = 0; j < 4; ++j) acc2[i][j] = zero4;

#pragma unroll 1
  for (int s = 0; s < 24; ++s) {
    const int tap = s >> 3, ks = s & 7;
    short8 bv[4];
    loadB4(Wb2, s, bv);
    const int xorv = ((tap + rlane) & 7) << 4;
    short8 av[4];
#pragma unroll
    for (int mi = 0; mi < 4; ++mi) {
      int a = (tap + (mi << 4) + rlane) * 512 + (ks << 6) + colp;
      av[mi] = *(const short8*)(lA + (a ^ xorv));
    }
#pragma unroll
    for (int mi = 0; mi < 4; ++mi)
#pragma unroll
      for (int ni = 0; ni < 4; ++ni)
        acc2[mi][ni] =
            __builtin_amdgcn_mfma_f32_16x16x32_bf16(av[mi], bv[ni], acc2[mi][ni], 0, 0, 0);
  }

  // ---- LN2 stats over 64 rows ----
  float bi2[4], gg2[4], bb2[4], wlv[4];
#pragma unroll
  for (int ni = 0; ni < 4; ++ni) {
    int col = cb0 + (ni << 4);
    bi2[ni] = b2[col]; gg2[ni] = g2[col]; bb2[ni] = be2[col];
    wlv[ni] = wl[col];
  }
#pragma unroll
  for (int mi = 0; mi < 4; ++mi) {
#pragma unroll
    for (int j = 0; j < 4; ++j) {
      float s = 0.f, s2 = 0.f;
#pragma unroll
      for (int ni = 0; ni < 4; ++ni) {
        float r = fmaxf(acc2[mi][ni][j] + bi2[ni], 0.f);
        s += r; s2 += r * r;
      }
#pragma unroll
      for (int d = 1; d < 16; d <<= 1) { s += __shfl_xor(s, d); s2 += __shfl_xor(s2, d); }
      if ((lane & 15) == 0) {
        int lr = (mi << 4) + rbase + j;
        lred[lr * 8 + wn] = s;
        lred[lr * 8 + 4 + wn] = s2;
      }
    }
  }
  __syncthreads();
  if (tid < 64) {
    float s = lred[tid * 8] + lred[tid * 8 + 1] + lred[tid * 8 + 2] + lred[tid * 8 + 3];
    float s2 = lred[tid * 8 + 4] + lred[tid * 8 + 5] + lred[tid * 8 + 6] + lred[tid * 8 + 7];
    float mean = s * (1.f / 256.f);
    float var = fmaxf(s2 * (1.f / 256.f) - mean * mean, 0.f);
    lstat[tid * 2] = mean;
    lstat[tid * 2 + 1] = rsqrtf(var + 1e-5f);
  }
  __syncthreads();

  // ---- LN2 apply + Linear(F->1) + ReLU ----
#pragma unroll
  for (int mi = 0; mi < 4; ++mi) {
#pragma unroll
    for (int j = 0; j < 4; ++j) {
      int lr = (mi << 4) + rbase + j;
      float mean = lstat[lr * 2], rstd = lstat[lr * 2 + 1];
      float ds = 0.f;
#pragma unroll
      for (int ni = 0; ni < 4; ++ni) {
        float r = fmaxf(acc2[mi][ni][j] + bi2[ni], 0.f);
        ds += ((r - mean) * rstd * gg2[ni] + bb2[ni]) * wlv[ni];
      }
#pragma unroll
      for (int d = 1; d < 16; d <<= 1) ds += __shfl_xor(ds, d);
      if ((lane & 15) == 0) lred[lr * 8 + wn] = ds;
    }
  }
  __syncthreads();
  if (tid < 64) {
    float z = lred[tid * 8] + lred[tid * 8 + 1] + lred[tid * 8 + 2] + lred[tid * 8 + 3] + blp[0];
    Sout[(size_t)b * L + t0 + tid] = fmaxf(z, 0.f);
  }
}

extern "C" void kernel_launch(void* const* d_in, const int* in_sizes, int n_in,
                              void* d_out, int out_size, void* d_ws, size_t ws_size,
                              hipStream_t stream) {
  const float* x = (const float*)d_in[0];
  const int* dur = (const int*)d_in[1];
  const float* tp = (const float*)d_in[2];
  const float* te = (const float*)d_in[3];
  const float* pq = (const float*)d_in[5];
  const float* eq = (const float*)d_in[6];
  const float* pemb = (const float*)d_in[37];
  const float* eemb = (const float*)d_in[38];

  char* ws = (char*)d_ws;
  __hip_bfloat16* wpb = (__hip_bfloat16*)ws;                 // 6 x 196608 bf16 (fragment-linear)
  __hip_bfloat16* wp[6];
  for (int i = 0; i < 6; ++i) wp[i] = wpb + (size_t)i * 196608;
  __hip_bfloat16* xb = (__hip_bfloat16*)(ws + 2359296);      // [32][258][256]
  // ws + 6586368 .. 10813440 intentionally unused (guard slack for halo overreads)
  __hip_bfloat16* M1 = (__hip_bfloat16*)(ws + 10813440);     // [32][2050][256]
  __hip_bfloat16* M2 = (__hip_bfloat16*)(ws + 44400640);     // [32][2050][256]

  float* out = (float*)d_out;

  zero2_kernel<<<192, 256, 0, stream>>>(xb, M1, M2);
  packfrag_kernel<<<576, 256, 0, stream>>>((const float*)d_in[7], (const float*)d_in[11],
                                           (const float*)d_in[17], (const float*)d_in[21],
                                           (const float*)d_in[27], (const float*)d_in[31], wpb);
  cvt_pad_kernel<<<2048, 256, 0, stream>>>(x, xb);

  // duration predictor (fused conv1+conv2, L=256): xb -> durations
  fused_pred<<<128, 256, 0, stream>>>(xb, wp[0], wp[1], (const float*)d_in[8],
                                      (const float*)d_in[9], (const float*)d_in[10],
                                      (const float*)d_in[12], (const float*)d_in[13],
                                      (const float*)d_in[14], (const float*)d_in[15],
                                      (const float*)d_in[16], out + DUR_OFF, 256);

  // length regulate (true durations) -> M1 bf16; mel_len
  gather_kernel<<<1024, 256, 0, stream>>>(xb, dur, M1, out + MEL_OFF);

  // pitch predictor (fused, L=2048): M1 -> pitches
  fused_pred<<<1024, 256, 0, stream>>>(M1, wp[2], wp[3], (const float*)d_in[18],
                                       (const float*)d_in[19], (const float*)d_in[20],
                                       (const float*)d_in[22], (const float*)d_in[23],
                                       (const float*)d_in[24], (const float*)d_in[25],
                                       (const float*)d_in[26], out + PIT_OFF, 2048);

  // fused embedding adds: M2 = bf16(M1+pemb), out = M1+pemb+eemb (f32)
  addemb_kernel<<<1024, 256, 0, stream>>>(tp, te, pq, eq, pemb, eemb, M1, M2, out);

  // energy predictor (fused, L=2048): M2 -> energies
  fused_pred<<<1024, 256, 0, stream>>>(M2, wp[4], wp[5], (const float*)d_in[28],
                                       (const float*)d_in[29], (const float*)d_in[30],
                                       (const float*)d_in[32], (const float*)d_in[33],
                                       (const float*)d_in[34], (const float*)d_in[35],
                                       (const float*)d_in[36], out + ENE_OFF, 2048);
}